// Round 3
// baseline (1534.725 us; speedup 1.0000x reference)
//
#include <hip/hip_runtime.h>
#include <stdint.h>

#define N_ANCH 147456
#define NGT 128

// ctl (uint32) layout inside d_ws after the label bytes
#define CTL_CNT    0      // [2] cntPos, cntNeg
#define CTL_SEL    2      // 2 ch x 6 {B, cumAbove, keep, keepAll, T, needAtT}
#define CTL_EQCNT  14     // [2]
#define CTL_EQL    16     // 2 x 256 equal-key index lists
#define CTL_COARSE 528    // 2 x 4096
#define CTL_FINE   8720   // 2 x 2048
#define CTL_WORDS  12816

__constant__ float c_base[9][4] = {
  {-84.f,-40.f,99.f,55.f},     // r=0.5 s=8
  {-176.f,-88.f,191.f,103.f},  // r=0.5 s=16
  {-360.f,-184.f,375.f,199.f}, // r=0.5 s=32
  {-56.f,-56.f,71.f,71.f},     // r=1   s=8
  {-120.f,-120.f,135.f,135.f}, // r=1   s=16
  {-248.f,-248.f,263.f,263.f}, // r=1   s=32
  {-36.f,-80.f,51.f,95.f},     // r=2   s=8
  {-80.f,-168.f,95.f,183.f},   // r=2   s=16
  {-168.f,-344.f,183.f,359.f}, // r=2   s=32
};

__host__ __device__ inline uint32_t rotl32(uint32_t v, int d){ return (v<<d)|(v>>(32-d)); }

// JAX Threefry-2x32, 20 rounds (5 groups of 4)
__host__ __device__ inline void tf2x32(uint32_t k0, uint32_t k1, uint32_t x0, uint32_t x1,
                                       uint32_t* o0, uint32_t* o1){
  uint32_t ks0=k0, ks1=k1, ks2=k0^k1^0x1BD11BDAu;
  x0 += ks0; x1 += ks1;
  #define TFR(r) { x0 += x1; x1 = rotl32(x1,(r)); x1 ^= x0; }
  TFR(13) TFR(15) TFR(26) TFR(6)   x0+=ks1; x1+=ks2+1u;
  TFR(17) TFR(29) TFR(16) TFR(24)  x0+=ks2; x1+=ks0+2u;
  TFR(13) TFR(15) TFR(26) TFR(6)   x0+=ks0; x1+=ks1+3u;
  TFR(17) TFR(29) TFR(16) TFR(24)  x0+=ks1; x1+=ks2+4u;
  TFR(13) TFR(15) TFR(26) TFR(6)   x0+=ks2; x1+=ks0+5u;
  #undef TFR
  *o0=x0; *o1=x1;
}

// jax_threefry_partitionable=True (default since JAX 0.4.36):
// random_bits(key,32,(n,)) for element j: enc(hi=0, lo=j) -> o0 ^ o1.
// uniform ordering key = top-23 bits of that.
__device__ inline uint32_t rand_m23(uint32_t k0, uint32_t k1, int j){
  uint32_t a, b;
  tf2x32(k0, k1, 0u, (uint32_t)j, &a, &b);
  return (a ^ b) >> 9;
}

__device__ inline void anchor_box(int i, float* ax1, float* ay1, float* ax2, float* ay2){
  int k = i / 9; int t = i - k*9;
  float sx = 16.0f * (float)(k & 127);
  float sy = 16.0f * (float)(k >> 7);
  *ax1 = c_base[t][0] + sx; *ay1 = c_base[t][1] + sy;
  *ax2 = c_base[t][2] + sx; *ay2 = c_base[t][3] + sy;
}

// IoU with +1 convention; __fmul_rn pins rounding so K1/K2 agree bitwise
__device__ inline float iou_box(float ax1,float ay1,float ax2,float ay2,
                                float bx1,float by1,float bx2,float by2){
  float iw = fminf(ax2,bx2) - fmaxf(ax1,bx1) + 1.0f; iw = fmaxf(iw, 0.0f);
  float ih = fminf(ay2,by2) - fmaxf(ay1,by1) + 1.0f; ih = fmaxf(ih, 0.0f);
  float inter = __fmul_rn(iw, ih);
  float areaA = __fmul_rn(ax2-ax1+1.0f, ay2-ay1+1.0f);
  float areaB = __fmul_rn(bx2-bx1+1.0f, by2-by1+1.0f);
  return inter / ((areaA + areaB) - inter);
}

// K1: per-anchor max/argmax over gt, stage labels, targets (float4 out)
__global__ __launch_bounds__(256) void k1_anchor(const float* __restrict__ gt,
                                                 const float* __restrict__ meta,
                                                 signed char* __restrict__ lab,
                                                 float* __restrict__ out){
  __shared__ float sg[NGT*4];
  for (int t = threadIdx.x; t < NGT*4; t += 256) sg[t] = gt[t];
  __syncthreads();
  int i = blockIdx.x*256 + threadIdx.x;
  float W = meta[1], H = meta[0];
  float ax1,ay1,ax2,ay2;
  anchor_box(i,&ax1,&ay1,&ax2,&ay2);
  bool inside = (ax1 >= 0.0f) && (ay1 >= 0.0f) && (ax2 < W) && (ay2 < H);
  float best = -1.0f; int arg = 0;   // outside: overlaps all -1 -> argmax 0
  if (inside){
    best = -2.0f;
    for (int g = 0; g < NGT; ++g){
      float ov = iou_box(ax1,ay1,ax2,ay2, sg[4*g],sg[4*g+1],sg[4*g+2],sg[4*g+3]);
      if (ov > best){ best = ov; arg = g; }   // strict > = first-occurrence argmax
    }
  }
  signed char L = -1;
  if (best >= 0.7f) L = 1;
  else if (inside && best < 0.3f) L = 0;
  lab[i] = L;
  float4 t4 = make_float4(0.f, 0.f, 0.f, 0.f);
  if (inside){
    float bx1=sg[4*arg], by1=sg[4*arg+1], bx2=sg[4*arg+2], by2=sg[4*arg+3];
    float ew = ax2-ax1+1.0f, eh = ay2-ay1+1.0f;
    float ecx = ax1 + 0.5f*ew, ecy = ay1 + 0.5f*eh;
    float gw = bx2-bx1+1.0f, gh = by2-by1+1.0f;
    float gcx = bx1 + 0.5f*gw, gcy = by1 + 0.5f*gh;
    t4.x = (gcx-ecx)/ew; t4.y = (gcy-ecy)/eh;
    t4.z = logf(gw/ew);  t4.w = logf(gh/eh);
  }
  *reinterpret_cast<float4*>(out + N_ANCH + 4*(size_t)i) = t4;
}

// K2: per-gt argmax over anchors (min index on ties) -> label = 1
__global__ __launch_bounds__(256) void k2_gtmax(const float* __restrict__ gt,
                                                const float* __restrict__ meta,
                                                signed char* __restrict__ lab){
  int g = blockIdx.x;
  float bx1=gt[4*g], by1=gt[4*g+1], bx2=gt[4*g+2], by2=gt[4*g+3];
  float W = meta[1], H = meta[0];
  float best = -2.0f; int bi = N_ANCH - 1;
  for (int i = threadIdx.x; i < N_ANCH; i += 256){
    float ax1,ay1,ax2,ay2;
    anchor_box(i,&ax1,&ay1,&ax2,&ay2);
    bool inside = (ax1 >= 0.0f) && (ay1 >= 0.0f) && (ax2 < W) && (ay2 < H);
    float ov = inside ? iou_box(ax1,ay1,ax2,ay2,bx1,by1,bx2,by2) : -1.0f;
    if (ov > best){ best = ov; bi = i; }   // ascending i -> strict > keeps min idx
  }
  __shared__ float sv[256]; __shared__ int si[256];
  sv[threadIdx.x]=best; si[threadIdx.x]=bi;
  __syncthreads();
  for (int s = 128; s > 0; s >>= 1){
    if ((int)threadIdx.x < s){
      float v2 = sv[threadIdx.x+s]; int i2 = si[threadIdx.x+s];
      if (v2 > sv[threadIdx.x] || (v2 == sv[threadIdx.x] && i2 < si[threadIdx.x])){
        sv[threadIdx.x]=v2; si[threadIdx.x]=i2;
      }
    }
    __syncthreads();
  }
  if (threadIdx.x == 0) lab[si[0]] = 1;   // dup writes of 1 are benign
}

// K3: counts + coarse histogram of 23-bit keys per channel
__global__ __launch_bounds__(256) void k3_count(const signed char* __restrict__ lab,
                                                uint32_t* __restrict__ ctl,
                                                uint32_t pk0,uint32_t pk1,uint32_t nk0,uint32_t nk1){
  int i = blockIdx.x*256 + threadIdx.x;
  int L = lab[i];
  if (L == 1){
    uint32_t m = rand_m23(pk0, pk1, i);
    atomicAdd(&ctl[CTL_CNT+0], 1u);
    atomicAdd(&ctl[CTL_COARSE + (m>>11)], 1u);
  } else if (L == 0){
    uint32_t m = rand_m23(nk0, nk1, i);
    atomicAdd(&ctl[CTL_CNT+1], 1u);
    atomicAdd(&ctl[CTL_COARSE + 4096 + (m>>11)], 1u);
  }
}

// K4: per-channel keep count + coarse boundary bin
__global__ void k4_coarse(uint32_t* __restrict__ ctl){
  int ch = threadIdx.x;
  if (ch >= 2) return;
  uint32_t cntP = ctl[CTL_CNT+0];
  uint32_t cnt  = ctl[CTL_CNT+ch];
  uint32_t keepP = cntP < 128u ? cntP : 128u;                       // min(n_pos,128)
  uint32_t keep  = (ch==0) ? keepP
                           : ((cnt < 256u-keepP) ? cnt : 256u-keepP); // min(n_neg,256-n_pos)
  uint32_t* sel = ctl + CTL_SEL + ch*6;
  sel[2] = keep;
  if (keep >= cnt){ sel[3] = 1u; return; }   // keep everything
  sel[3] = 0u;
  const uint32_t* hist = ctl + CTL_COARSE + ch*4096;
  uint32_t cum = 0; int B = 0;
  for (int b = 4095; b >= 0; --b){
    uint32_t c = hist[b];
    if (cum + c >= keep){ B = b; break; }
    cum += c;
  }
  sel[0] = (uint32_t)B; sel[1] = cum;
}

// K5: fine histogram inside the boundary bin
__global__ __launch_bounds__(256) void k5_fine(const signed char* __restrict__ lab,
                                               uint32_t* __restrict__ ctl,
                                               uint32_t pk0,uint32_t pk1,uint32_t nk0,uint32_t nk1){
  int i = blockIdx.x*256 + threadIdx.x;
  int L = lab[i];
  int ch = (L==1) ? 0 : (L==0) ? 1 : -1;
  if (ch < 0) return;
  const uint32_t* sel = ctl + CTL_SEL + ch*6;
  if (sel[3]) return;
  uint32_t m = rand_m23(ch==0?pk0:nk0, ch==0?pk1:nk1, i);
  if ((m>>11) == sel[0]) atomicAdd(&ctl[CTL_FINE + ch*2048 + (m & 2047u)], 1u);
}

// K6: exact threshold key T and how many to keep at T
__global__ void k6_scan(uint32_t* __restrict__ ctl){
  int ch = threadIdx.x;
  if (ch >= 2) return;
  uint32_t* sel = ctl + CTL_SEL + ch*6;
  if (sel[3]) return;
  uint32_t keepRem = sel[2] - sel[1];
  const uint32_t* fine = ctl + CTL_FINE + ch*2048;
  uint32_t cum = 0; int L = 0;
  for (int b = 2047; b >= 0; --b){
    uint32_t c = fine[b];
    if (cum + c >= keepRem){ L = b; break; }
    cum += c;
  }
  sel[4] = (sel[0] << 11) | (uint32_t)L;
  sel[5] = keepRem - cum;   // >= 1
}

// K7: write final labels (f32) except exact-tie indices (collected for K8)
__global__ __launch_bounds__(256) void k7_final(const signed char* __restrict__ lab,
                                                float* __restrict__ out,
                                                uint32_t* __restrict__ ctl,
                                                uint32_t pk0,uint32_t pk1,uint32_t nk0,uint32_t nk1){
  int i = blockIdx.x*256 + threadIdx.x;
  int L = lab[i];
  float v = (float)L;
  int ch = (L==1) ? 0 : (L==0) ? 1 : -1;
  if (ch >= 0){
    const uint32_t* sel = ctl + CTL_SEL + ch*6;
    if (!sel[3]){
      uint32_t m = rand_m23(ch==0?pk0:nk0, ch==0?pk1:nk1, i);
      uint32_t T = sel[4];
      if (m < T) v = -1.0f;               // demoted
      else if (m == T){                   // tie at threshold: resolve by index in K8
        uint32_t pos = atomicAdd(&ctl[CTL_EQCNT+ch], 1u);
        if (pos < 256u) ctl[CTL_EQL + ch*256 + pos] = (uint32_t)i;
        return;
      }
    }
  }
  out[i] = v;
}

// K8: sort tie lists by index (stable argsort tie-break), keep first needAtT
__global__ void k8_eq(float* __restrict__ out, uint32_t* __restrict__ ctl){
  if (threadIdx.x != 0) return;
  for (int ch = 0; ch < 2; ++ch){
    uint32_t n = ctl[CTL_EQCNT+ch]; if (n > 256u) n = 256u;
    uint32_t* lst = ctl + CTL_EQL + ch*256;
    uint32_t need = ctl[CTL_SEL + ch*6 + 5];
    for (uint32_t a = 1; a < n; ++a){       // insertion sort ascending (n is tiny)
      uint32_t v = lst[a]; int b = (int)a - 1;
      while (b >= 0 && lst[b] > v){ lst[b+1] = lst[b]; --b; }
      lst[b+1] = v;
    }
    float kv = (ch==0) ? 1.0f : 0.0f;
    for (uint32_t a = 0; a < n; ++a)
      out[lst[a]] = (a < need) ? kv : -1.0f;
  }
}

extern "C" void kernel_launch(void* const* d_in, const int* in_sizes, int n_in,
                              void* d_out, int out_size, void* d_ws, size_t ws_size,
                              hipStream_t stream) {
  const float* gt   = (const float*)d_in[1];   // (1,128,4)
  const float* meta = (const float*)d_in[2];   // (1,3) = {H, W, scale}
  float* out = (float*)d_out;                  // labels (147456) + targets (147456*4)
  signed char* lab = (signed char*)d_ws;                       // N_ANCH bytes
  uint32_t* ctl = (uint32_t*)((char*)d_ws + N_ANCH);           // CTL_WORDS u32

  hipMemsetAsync(ctl, 0, CTL_WORDS * sizeof(uint32_t), stream);

  // jax.random.key(42) = (0,42); partitionable split (foldlike):
  // counts (hi,lo) = (0,0) and (0,1); key_i = (o0, o1) of enc(0, i).
  uint32_t a0,a1,b0,b1;
  tf2x32(0u, 42u, 0u, 0u, &a0, &a1);   // k1 (positives)
  tf2x32(0u, 42u, 0u, 1u, &b0, &b1);   // k2 (negatives)

  k1_anchor<<<576, 256, 0, stream>>>(gt, meta, lab, out);
  k2_gtmax <<<NGT, 256, 0, stream>>>(gt, meta, lab);
  k3_count <<<576, 256, 0, stream>>>(lab, ctl, a0, a1, b0, b1);
  k4_coarse<<<1, 64, 0, stream>>>(ctl);
  k5_fine  <<<576, 256, 0, stream>>>(lab, ctl, a0, a1, b0, b1);
  k6_scan  <<<1, 64, 0, stream>>>(ctl);
  k7_final <<<576, 256, 0, stream>>>(lab, out, ctl, a0, a1, b0, b1);
  k8_eq    <<<1, 1, 0, stream>>>(out, ctl);
}

// Round 4
// 131.098 us; speedup vs baseline: 11.7067x; 11.7067x over previous
//
#include <hip/hip_runtime.h>
#include <stdint.h>

#define N_ANCH 147456
#define NGT 128

// ctl (uint32) layout inside d_ws after the label bytes
#define CTL_SEL    2      // 2 ch x 6 {B, cumAbove, keep, keepAll, T, needAtT}
#define CTL_EQCNT  14     // [2]
#define CTL_EQL    16     // 2 x 256 equal-key index lists
#define CTL_COARSE 528    // 2 x 4096
#define CTL_FINE   8720   // 2 x 2048
#define CTL_WORDS  12816

__constant__ float c_base[9][4] = {
  {-84.f,-40.f,99.f,55.f},     // r=0.5 s=8
  {-176.f,-88.f,191.f,103.f},  // r=0.5 s=16
  {-360.f,-184.f,375.f,199.f}, // r=0.5 s=32
  {-56.f,-56.f,71.f,71.f},     // r=1   s=8
  {-120.f,-120.f,135.f,135.f}, // r=1   s=16
  {-248.f,-248.f,263.f,263.f}, // r=1   s=32
  {-36.f,-80.f,51.f,95.f},     // r=2   s=8
  {-80.f,-168.f,95.f,183.f},   // r=2   s=16
  {-168.f,-344.f,183.f,359.f}, // r=2   s=32
};

__host__ __device__ inline uint32_t rotl32(uint32_t v, int d){ return (v<<d)|(v>>(32-d)); }

// JAX Threefry-2x32, 20 rounds (5 groups of 4)
__host__ __device__ inline void tf2x32(uint32_t k0, uint32_t k1, uint32_t x0, uint32_t x1,
                                       uint32_t* o0, uint32_t* o1){
  uint32_t ks0=k0, ks1=k1, ks2=k0^k1^0x1BD11BDAu;
  x0 += ks0; x1 += ks1;
  #define TFR(r) { x0 += x1; x1 = rotl32(x1,(r)); x1 ^= x0; }
  TFR(13) TFR(15) TFR(26) TFR(6)   x0+=ks1; x1+=ks2+1u;
  TFR(17) TFR(29) TFR(16) TFR(24)  x0+=ks2; x1+=ks0+2u;
  TFR(13) TFR(15) TFR(26) TFR(6)   x0+=ks0; x1+=ks1+3u;
  TFR(17) TFR(29) TFR(16) TFR(24)  x0+=ks1; x1+=ks2+4u;
  TFR(13) TFR(15) TFR(26) TFR(6)   x0+=ks2; x1+=ks0+5u;
  #undef TFR
  *o0=x0; *o1=x1;
}

// jax_threefry_partitionable=True (default since JAX 0.4.36):
// random_bits(key,32,(n,)) element j: enc(hi=0, lo=j) -> o0 ^ o1; key = top 23 bits.
__device__ inline uint32_t rand_m23(uint32_t k0, uint32_t k1, int j){
  uint32_t a, b;
  tf2x32(k0, k1, 0u, (uint32_t)j, &a, &b);
  return (a ^ b) >> 9;
}

__device__ inline void anchor_box(int i, float* ax1, float* ay1, float* ax2, float* ay2){
  int k = i / 9; int t = i - k*9;
  float sx = 16.0f * (float)(k & 127);
  float sy = 16.0f * (float)(k >> 7);
  *ax1 = c_base[t][0] + sx; *ay1 = c_base[t][1] + sy;
  *ax2 = c_base[t][2] + sx; *ay2 = c_base[t][3] + sy;
}

// IoU with +1 convention; __fmul_rn pins rounding so K1/K2 agree bitwise
__device__ inline float iou_box(float ax1,float ay1,float ax2,float ay2,
                                float bx1,float by1,float bx2,float by2){
  float iw = fminf(ax2,bx2) - fmaxf(ax1,bx1) + 1.0f; iw = fmaxf(iw, 0.0f);
  float ih = fminf(ay2,by2) - fmaxf(ay1,by1) + 1.0f; ih = fmaxf(ih, 0.0f);
  float inter = __fmul_rn(iw, ih);
  float areaA = __fmul_rn(ax2-ax1+1.0f, ay2-ay1+1.0f);
  float areaB = __fmul_rn(bx2-bx1+1.0f, by2-by1+1.0f);
  return inter / ((areaA + areaB) - inter);
}

// K1: per-anchor max/argmax over gt, stage labels, targets (float4 out)
__global__ __launch_bounds__(256) void k1_anchor(const float* __restrict__ gt,
                                                 const float* __restrict__ meta,
                                                 signed char* __restrict__ lab,
                                                 float* __restrict__ out){
  __shared__ float sg[NGT*4];
  for (int t = threadIdx.x; t < NGT*4; t += 256) sg[t] = gt[t];
  __syncthreads();
  int i = blockIdx.x*256 + threadIdx.x;
  float W = meta[1], H = meta[0];
  float ax1,ay1,ax2,ay2;
  anchor_box(i,&ax1,&ay1,&ax2,&ay2);
  bool inside = (ax1 >= 0.0f) && (ay1 >= 0.0f) && (ax2 < W) && (ay2 < H);
  float best = -1.0f; int arg = 0;   // outside: overlaps all -1 -> argmax 0
  if (inside){
    best = -2.0f;
    for (int g = 0; g < NGT; ++g){
      float ov = iou_box(ax1,ay1,ax2,ay2, sg[4*g],sg[4*g+1],sg[4*g+2],sg[4*g+3]);
      if (ov > best){ best = ov; arg = g; }   // strict > = first-occurrence argmax
    }
  }
  signed char L = -1;
  if (best >= 0.7f) L = 1;
  else if (inside && best < 0.3f) L = 0;
  lab[i] = L;
  float4 t4 = make_float4(0.f, 0.f, 0.f, 0.f);
  if (inside){
    float bx1=sg[4*arg], by1=sg[4*arg+1], bx2=sg[4*arg+2], by2=sg[4*arg+3];
    float ew = ax2-ax1+1.0f, eh = ay2-ay1+1.0f;
    float ecx = ax1 + 0.5f*ew, ecy = ay1 + 0.5f*eh;
    float gw = bx2-bx1+1.0f, gh = by2-by1+1.0f;
    float gcx = bx1 + 0.5f*gw, gcy = by1 + 0.5f*gh;
    t4.x = (gcx-ecx)/ew; t4.y = (gcy-ecy)/eh;
    t4.z = logf(gw/ew);  t4.w = logf(gh/eh);
  }
  *reinterpret_cast<float4*>(out + N_ANCH + 4*(size_t)i) = t4;
}

// K2: per-gt argmax over anchors (min index on ties) -> label = 1
__global__ __launch_bounds__(1024) void k2_gtmax(const float* __restrict__ gt,
                                                 const float* __restrict__ meta,
                                                 signed char* __restrict__ lab){
  int g = blockIdx.x;
  float bx1=gt[4*g], by1=gt[4*g+1], bx2=gt[4*g+2], by2=gt[4*g+3];
  float W = meta[1], H = meta[0];
  float best = -2.0f; int bi = N_ANCH - 1;
  for (int i = threadIdx.x; i < N_ANCH; i += 1024){
    float ax1,ay1,ax2,ay2;
    anchor_box(i,&ax1,&ay1,&ax2,&ay2);
    bool inside = (ax1 >= 0.0f) && (ay1 >= 0.0f) && (ax2 < W) && (ay2 < H);
    float ov = inside ? iou_box(ax1,ay1,ax2,ay2,bx1,by1,bx2,by2) : -1.0f;
    if (ov > best){ best = ov; bi = i; }   // ascending i -> strict > keeps min idx
  }
  __shared__ float sv[1024]; __shared__ int si[1024];
  sv[threadIdx.x]=best; si[threadIdx.x]=bi;
  __syncthreads();
  for (int s = 512; s > 0; s >>= 1){
    if ((int)threadIdx.x < s){
      float v2 = sv[threadIdx.x+s]; int i2 = si[threadIdx.x+s];
      if (v2 > sv[threadIdx.x] || (v2 == sv[threadIdx.x] && i2 < si[threadIdx.x])){
        sv[threadIdx.x]=v2; si[threadIdx.x]=i2;
      }
    }
    __syncthreads();
  }
  if (threadIdx.x == 0) lab[si[0]] = 1;   // dup writes of 1 are benign
}

// K3: coarse histogram of 23-bit keys per channel (spread atomics only;
// per-channel counts are derived from the histogram in K4 — no hot-address atomics)
__global__ __launch_bounds__(256) void k3_count(const signed char* __restrict__ lab,
                                                uint32_t* __restrict__ ctl,
                                                uint32_t pk0,uint32_t pk1,uint32_t nk0,uint32_t nk1){
  int i = blockIdx.x*256 + threadIdx.x;
  int L = lab[i];
  if (L < 0) return;
  int ch = (L==1) ? 0 : 1;
  uint32_t m = rand_m23(ch==0?pk0:nk0, ch==0?pk1:nk1, i);
  atomicAdd(&ctl[CTL_COARSE + ch*4096 + (m>>11)], 1u);
}

// K4: per-channel count (histogram reduction), keep count, coarse boundary bin.
// 1 block x 256 threads: threads t<128 own ch0 groups, t>=128 ch1; 32 bins/group.
__global__ __launch_bounds__(256) void k4_coarse(uint32_t* __restrict__ ctl){
  __shared__ uint32_t gsum[256];
  __shared__ uint32_t scnt[2];
  int ch = threadIdx.x >> 7, grp = threadIdx.x & 127;
  const uint32_t* hist = ctl + CTL_COARSE + ch*4096;
  uint32_t s = 0;
  #pragma unroll
  for (int b = 0; b < 32; ++b) s += hist[grp*32 + b];
  gsum[threadIdx.x] = s;
  __syncthreads();
  if ((threadIdx.x & 127) == 0){
    uint32_t cnt = 0;
    for (int gq = 0; gq < 128; ++gq) cnt += gsum[ch*128 + gq];
    scnt[ch] = cnt;
  }
  __syncthreads();
  if (threadIdx.x < 2){
    int c = threadIdx.x;
    uint32_t cntP = scnt[0];
    uint32_t cnt  = scnt[c];
    uint32_t keepP = cntP < 128u ? cntP : 128u;                         // min(n_pos,128)
    uint32_t keep  = (c==0) ? keepP
                            : ((cnt < 256u-keepP) ? cnt : 256u-keepP);  // min(n_neg,256-n_pos)
    uint32_t* sel = ctl + CTL_SEL + c*6;
    sel[2] = keep;
    if (keep >= cnt){ sel[3] = 1u; }
    else {
      sel[3] = 0u;
      // suffix scan: groups from top
      uint32_t cum = 0; int G = 0;
      for (int gq = 127; gq >= 0; --gq){
        uint32_t gc = gsum[c*128 + gq];
        if (cum + gc >= keep){ G = gq; break; }
        cum += gc;
      }
      const uint32_t* h = ctl + CTL_COARSE + c*4096;
      int B = G*32;
      for (int b = G*32+31; b >= G*32; --b){
        uint32_t bc = h[b];
        if (cum + bc >= keep){ B = b; break; }
        cum += bc;
      }
      sel[0] = (uint32_t)B; sel[1] = cum;
    }
  }
}

// K5: fine histogram inside the boundary bin
__global__ __launch_bounds__(256) void k5_fine(const signed char* __restrict__ lab,
                                               uint32_t* __restrict__ ctl,
                                               uint32_t pk0,uint32_t pk1,uint32_t nk0,uint32_t nk1){
  int i = blockIdx.x*256 + threadIdx.x;
  int L = lab[i];
  int ch = (L==1) ? 0 : (L==0) ? 1 : -1;
  if (ch < 0) return;
  const uint32_t* sel = ctl + CTL_SEL + ch*6;
  if (sel[3]) return;
  uint32_t m = rand_m23(ch==0?pk0:nk0, ch==0?pk1:nk1, i);
  if ((m>>11) == sel[0]) atomicAdd(&ctl[CTL_FINE + ch*2048 + (m & 2047u)], 1u);
}

// K6: exact threshold key T and count kept at T.
// 1 block x 256 threads: t<64 ch0 groups, 64<=t<128 ch1; 32 bins/group (2048 bins/ch).
__global__ __launch_bounds__(256) void k6_scan(uint32_t* __restrict__ ctl){
  __shared__ uint32_t gsum[128];
  int ch = (threadIdx.x >> 6) & 1, grp = threadIdx.x & 63;
  if (threadIdx.x < 128){
    const uint32_t* fine = ctl + CTL_FINE + ch*2048;
    uint32_t s = 0;
    #pragma unroll
    for (int b = 0; b < 32; ++b) s += fine[grp*32 + b];
    gsum[threadIdx.x] = s;
  }
  __syncthreads();
  if (threadIdx.x < 2){
    int c = threadIdx.x;
    uint32_t* sel = ctl + CTL_SEL + c*6;
    if (!sel[3]){
      uint32_t keepRem = sel[2] - sel[1];
      uint32_t cum = 0; int G = 0;
      for (int gq = 63; gq >= 0; --gq){
        uint32_t gc = gsum[c*64 + gq];
        if (cum + gc >= keepRem){ G = gq; break; }
        cum += gc;
      }
      const uint32_t* fine = ctl + CTL_FINE + c*2048;
      int Lb = G*32;
      for (int b = G*32+31; b >= G*32; --b){
        uint32_t bc = fine[b];
        if (cum + bc >= keepRem){ Lb = b; break; }
        cum += bc;
      }
      sel[4] = (sel[0] << 11) | (uint32_t)Lb;
      sel[5] = keepRem - cum;   // >= 1
    }
  }
}

// K7: write final labels (f32) except exact-tie indices (collected for K8)
__global__ __launch_bounds__(256) void k7_final(const signed char* __restrict__ lab,
                                                float* __restrict__ out,
                                                uint32_t* __restrict__ ctl,
                                                uint32_t pk0,uint32_t pk1,uint32_t nk0,uint32_t nk1){
  int i = blockIdx.x*256 + threadIdx.x;
  int L = lab[i];
  float v = (float)L;
  int ch = (L==1) ? 0 : (L==0) ? 1 : -1;
  if (ch >= 0){
    const uint32_t* sel = ctl + CTL_SEL + ch*6;
    if (!sel[3]){
      uint32_t m = rand_m23(ch==0?pk0:nk0, ch==0?pk1:nk1, i);
      uint32_t T = sel[4];
      if (m < T) v = -1.0f;               // demoted
      else if (m == T){                   // tie at threshold: resolve by index in K8
        uint32_t pos = atomicAdd(&ctl[CTL_EQCNT+ch], 1u);
        if (pos < 256u) ctl[CTL_EQL + ch*256 + pos] = (uint32_t)i;
        return;
      }
    }
  }
  out[i] = v;
}

// K8: sort tie lists by index (stable argsort tie-break), keep first needAtT
__global__ void k8_eq(float* __restrict__ out, uint32_t* __restrict__ ctl){
  if (threadIdx.x != 0) return;
  for (int ch = 0; ch < 2; ++ch){
    uint32_t n = ctl[CTL_EQCNT+ch]; if (n > 256u) n = 256u;
    uint32_t* lst = ctl + CTL_EQL + ch*256;
    uint32_t need = ctl[CTL_SEL + ch*6 + 5];
    for (uint32_t a = 1; a < n; ++a){       // insertion sort ascending (n is tiny)
      uint32_t v = lst[a]; int b = (int)a - 1;
      while (b >= 0 && lst[b] > v){ lst[b+1] = lst[b]; --b; }
      lst[b+1] = v;
    }
    float kv = (ch==0) ? 1.0f : 0.0f;
    for (uint32_t a = 0; a < n; ++a)
      out[lst[a]] = (a < need) ? kv : -1.0f;
  }
}

extern "C" void kernel_launch(void* const* d_in, const int* in_sizes, int n_in,
                              void* d_out, int out_size, void* d_ws, size_t ws_size,
                              hipStream_t stream) {
  const float* gt   = (const float*)d_in[1];   // (1,128,4)
  const float* meta = (const float*)d_in[2];   // (1,3) = {H, W, scale}
  float* out = (float*)d_out;                  // labels (147456) + targets (147456*4)
  signed char* lab = (signed char*)d_ws;                       // N_ANCH bytes
  uint32_t* ctl = (uint32_t*)((char*)d_ws + N_ANCH);           // CTL_WORDS u32

  hipMemsetAsync(ctl, 0, CTL_WORDS * sizeof(uint32_t), stream);

  // jax.random.key(42) = (0,42); partitionable split (foldlike):
  // counts (hi,lo) = (0,0) and (0,1); key_i = (o0, o1) of enc(0, i).
  uint32_t a0,a1,b0,b1;
  tf2x32(0u, 42u, 0u, 0u, &a0, &a1);   // k1 (positives)
  tf2x32(0u, 42u, 0u, 1u, &b0, &b1);   // k2 (negatives)

  k1_anchor<<<576, 256, 0, stream>>>(gt, meta, lab, out);
  k2_gtmax <<<NGT, 1024, 0, stream>>>(gt, meta, lab);
  k3_count <<<576, 256, 0, stream>>>(lab, ctl, a0, a1, b0, b1);
  k4_coarse<<<1, 256, 0, stream>>>(ctl);
  k5_fine  <<<576, 256, 0, stream>>>(lab, ctl, a0, a1, b0, b1);
  k6_scan  <<<1, 256, 0, stream>>>(ctl);
  k7_final <<<576, 256, 0, stream>>>(lab, out, ctl, a0, a1, b0, b1);
  k8_eq    <<<1, 1, 0, stream>>>(out, ctl);
}

// Round 5
// 83.613 us; speedup vs baseline: 18.3550x; 1.5679x over previous
//
#include <hip/hip_runtime.h>
#include <stdint.h>

#define N_ANCH 147456
#define NGT 128

// ctl (uint32) layout inside d_ws after the label bytes
#define CTL_SEL    2      // 2 ch x 6 {B, cumAbove, keep, keepAll, T, needAtT}
#define CTL_EQCNT  14     // [2]
#define CTL_EQL    16     // 2 x 256 equal-key index lists
#define CTL_COARSE 528    // 2 x 4096
#define CTL_FINE   8720   // 2 x 2048
#define CTL_GTMAX  12816  // 128 x u64 (256 words, 8B-aligned: byte off 147456+51264)
#define CTL_WORDS  13072

__constant__ float c_base[9][4] = {
  {-84.f,-40.f,99.f,55.f},     // r=0.5 s=8
  {-176.f,-88.f,191.f,103.f},  // r=0.5 s=16
  {-360.f,-184.f,375.f,199.f}, // r=0.5 s=32
  {-56.f,-56.f,71.f,71.f},     // r=1   s=8
  {-120.f,-120.f,135.f,135.f}, // r=1   s=16
  {-248.f,-248.f,263.f,263.f}, // r=1   s=32
  {-36.f,-80.f,51.f,95.f},     // r=2   s=8
  {-80.f,-168.f,95.f,183.f},   // r=2   s=16
  {-168.f,-344.f,183.f,359.f}, // r=2   s=32
};

__host__ __device__ inline uint32_t rotl32(uint32_t v, int d){ return (v<<d)|(v>>(32-d)); }

// JAX Threefry-2x32, 20 rounds (5 groups of 4)
__host__ __device__ inline void tf2x32(uint32_t k0, uint32_t k1, uint32_t x0, uint32_t x1,
                                       uint32_t* o0, uint32_t* o1){
  uint32_t ks0=k0, ks1=k1, ks2=k0^k1^0x1BD11BDAu;
  x0 += ks0; x1 += ks1;
  #define TFR(r) { x0 += x1; x1 = rotl32(x1,(r)); x1 ^= x0; }
  TFR(13) TFR(15) TFR(26) TFR(6)   x0+=ks1; x1+=ks2+1u;
  TFR(17) TFR(29) TFR(16) TFR(24)  x0+=ks2; x1+=ks0+2u;
  TFR(13) TFR(15) TFR(26) TFR(6)   x0+=ks0; x1+=ks1+3u;
  TFR(17) TFR(29) TFR(16) TFR(24)  x0+=ks1; x1+=ks2+4u;
  TFR(13) TFR(15) TFR(26) TFR(6)   x0+=ks2; x1+=ks0+5u;
  #undef TFR
  *o0=x0; *o1=x1;
}

// jax_threefry_partitionable=True (default since JAX 0.4.36):
// random_bits(key,32,(n,)) element j: enc(hi=0, lo=j) -> o0 ^ o1; key = top 23 bits.
__device__ inline uint32_t rand_m23(uint32_t k0, uint32_t k1, int j){
  uint32_t a, b;
  tf2x32(k0, k1, 0u, (uint32_t)j, &a, &b);
  return (a ^ b) >> 9;
}

__device__ inline void anchor_box(int i, float* ax1, float* ay1, float* ax2, float* ay2){
  int k = i / 9; int t = i - k*9;
  float sx = 16.0f * (float)(k & 127);
  float sy = 16.0f * (float)(k >> 7);
  *ax1 = c_base[t][0] + sx; *ay1 = c_base[t][1] + sy;
  *ax2 = c_base[t][2] + sx; *ay2 = c_base[t][3] + sy;
}

// IoU with +1 convention; __fmul_rn pins rounding so K1/K2 agree bitwise
__device__ inline float iou_box(float ax1,float ay1,float ax2,float ay2,
                                float bx1,float by1,float bx2,float by2){
  float iw = fminf(ax2,bx2) - fmaxf(ax1,bx1) + 1.0f; iw = fmaxf(iw, 0.0f);
  float ih = fminf(ay2,by2) - fmaxf(ay1,by1) + 1.0f; ih = fmaxf(ih, 0.0f);
  float inter = __fmul_rn(iw, ih);
  float areaA = __fmul_rn(ax2-ax1+1.0f, ay2-ay1+1.0f);
  float areaB = __fmul_rn(bx2-bx1+1.0f, by2-by1+1.0f);
  return inter / ((areaA + areaB) - inter);
}

// K1: per-anchor max/argmax over gt, stage labels, targets (float4 out)
__global__ __launch_bounds__(256) void k1_anchor(const float* __restrict__ gt,
                                                 const float* __restrict__ meta,
                                                 signed char* __restrict__ lab,
                                                 float* __restrict__ out){
  __shared__ float sg[NGT*4];
  for (int t = threadIdx.x; t < NGT*4; t += 256) sg[t] = gt[t];
  __syncthreads();
  int i = blockIdx.x*256 + threadIdx.x;
  float W = meta[1], H = meta[0];
  float ax1,ay1,ax2,ay2;
  anchor_box(i,&ax1,&ay1,&ax2,&ay2);
  bool inside = (ax1 >= 0.0f) && (ay1 >= 0.0f) && (ax2 < W) && (ay2 < H);
  float best = -1.0f; int arg = 0;   // outside: overlaps all -1 -> argmax 0
  if (inside){
    best = -2.0f;
    for (int g = 0; g < NGT; ++g){
      float ov = iou_box(ax1,ay1,ax2,ay2, sg[4*g],sg[4*g+1],sg[4*g+2],sg[4*g+3]);
      if (ov > best){ best = ov; arg = g; }   // strict > = first-occurrence argmax
    }
  }
  signed char L = -1;
  if (best >= 0.7f) L = 1;
  else if (inside && best < 0.3f) L = 0;
  lab[i] = L;
  float4 t4 = make_float4(0.f, 0.f, 0.f, 0.f);
  if (inside){
    float bx1=sg[4*arg], by1=sg[4*arg+1], bx2=sg[4*arg+2], by2=sg[4*arg+3];
    float ew = ax2-ax1+1.0f, eh = ay2-ay1+1.0f;
    float ecx = ax1 + 0.5f*ew, ecy = ay1 + 0.5f*eh;
    float gw = bx2-bx1+1.0f, gh = by2-by1+1.0f;
    float gcx = bx1 + 0.5f*gw, gcy = by1 + 0.5f*gh;
    t4.x = (gcx-ecx)/ew; t4.y = (gcy-ecy)/eh;
    t4.z = logf(gw/ew);  t4.w = logf(gh/eh);
  }
  *reinterpret_cast<float4*>(out + N_ANCH + 4*(size_t)i) = t4;
}

// K2: per-gt argmax over anchors, 8 slice-blocks per gt, packed-u64 atomicMax.
// pack = (iou_bits << 32) | ~index  -> max = (max iou, then min index); iou >= 0.
__global__ __launch_bounds__(256) void k2_gtmax(const float* __restrict__ gt,
                                                const float* __restrict__ meta,
                                                unsigned long long* __restrict__ gmax){
  int g = blockIdx.x >> 3, slice = blockIdx.x & 7;
  float bx1=gt[4*g], by1=gt[4*g+1], bx2=gt[4*g+2], by2=gt[4*g+3];
  float W = meta[1], H = meta[0];
  float a0[9],a1[9],a2[9],a3[9];
  #pragma unroll
  for (int t=0;t<9;++t){ a0[t]=c_base[t][0]; a1[t]=c_base[t][1];
                         a2[t]=c_base[t][2]; a3[t]=c_base[t][3]; }
  float best = -2.0f; int bi = 0;
  int kbase = slice*2048 + threadIdx.x;
  #pragma unroll
  for (int j = 0; j < 8; ++j){
    int k = kbase + j*256;
    float sx = 16.0f * (float)(k & 127);
    float sy = 16.0f * (float)(k >> 7);
    #pragma unroll
    for (int t = 0; t < 9; ++t){
      float ax1=a0[t]+sx, ay1=a1[t]+sy, ax2=a2[t]+sx, ay2=a3[t]+sy;
      bool inside = (ax1 >= 0.0f) && (ay1 >= 0.0f) && (ax2 < W) && (ay2 < H);
      float ov = inside ? iou_box(ax1,ay1,ax2,ay2,bx1,by1,bx2,by2) : -1.0f;
      if (ov > best){ best = ov; bi = k*9 + t; }   // j,t ascending -> min idx on tie
    }
  }
  unsigned long long p = 0ull;
  if (best >= 0.0f)
    p = ((unsigned long long)__float_as_uint(best) << 32) | (uint32_t)(~(uint32_t)bi);
  __shared__ unsigned long long sred[256];
  sred[threadIdx.x] = p;
  __syncthreads();
  for (int s = 128; s > 0; s >>= 1){
    if ((int)threadIdx.x < s){
      unsigned long long q = sred[threadIdx.x + s];
      if (q > sred[threadIdx.x]) sred[threadIdx.x] = q;
    }
    __syncthreads();
  }
  if (threadIdx.x == 0 && sred[0]) atomicMax(&gmax[g], sred[0]);
}

// K2b: winners -> labels
__global__ void k2b_mark(const unsigned long long* __restrict__ gmax,
                         signed char* __restrict__ lab){
  int g = threadIdx.x;
  unsigned long long p = gmax[g];
  if (p){ uint32_t idx = ~(uint32_t)(p & 0xFFFFFFFFull); lab[idx] = 1; }
}

// K3: coarse histogram of 23-bit keys per channel (spread atomics only)
__global__ __launch_bounds__(256) void k3_count(const signed char* __restrict__ lab,
                                                uint32_t* __restrict__ ctl,
                                                uint32_t pk0,uint32_t pk1,uint32_t nk0,uint32_t nk1){
  int i = blockIdx.x*256 + threadIdx.x;
  int L = lab[i];
  if (L < 0) return;
  int ch = (L==1) ? 0 : 1;
  uint32_t m = rand_m23(ch==0?pk0:nk0, ch==0?pk1:nk1, i);
  atomicAdd(&ctl[CTL_COARSE + ch*4096 + (m>>11)], 1u);
}

// K4: per-channel count (histogram reduction), keep count, coarse boundary bin.
__global__ __launch_bounds__(256) void k4_coarse(uint32_t* __restrict__ ctl){
  __shared__ uint32_t gsum[256];
  __shared__ uint32_t scnt[2];
  int ch = threadIdx.x >> 7, grp = threadIdx.x & 127;
  const uint32_t* hist = ctl + CTL_COARSE + ch*4096;
  uint32_t s = 0;
  #pragma unroll
  for (int b = 0; b < 32; ++b) s += hist[grp*32 + b];
  gsum[threadIdx.x] = s;
  __syncthreads();
  if ((threadIdx.x & 127) == 0){
    uint32_t cnt = 0;
    for (int gq = 0; gq < 128; ++gq) cnt += gsum[ch*128 + gq];
    scnt[ch] = cnt;
  }
  __syncthreads();
  if (threadIdx.x < 2){
    int c = threadIdx.x;
    uint32_t cntP = scnt[0];
    uint32_t cnt  = scnt[c];
    uint32_t keepP = cntP < 128u ? cntP : 128u;                         // min(n_pos,128)
    uint32_t keep  = (c==0) ? keepP
                            : ((cnt < 256u-keepP) ? cnt : 256u-keepP);  // min(n_neg,256-n_pos)
    uint32_t* sel = ctl + CTL_SEL + c*6;
    sel[2] = keep;
    if (keep >= cnt){ sel[3] = 1u; }
    else {
      sel[3] = 0u;
      uint32_t cum = 0; int G = 0;
      for (int gq = 127; gq >= 0; --gq){
        uint32_t gc = gsum[c*128 + gq];
        if (cum + gc >= keep){ G = gq; break; }
        cum += gc;
      }
      const uint32_t* h = ctl + CTL_COARSE + c*4096;
      int B = G*32;
      for (int b = G*32+31; b >= G*32; --b){
        uint32_t bc = h[b];
        if (cum + bc >= keep){ B = b; break; }
        cum += bc;
      }
      sel[0] = (uint32_t)B; sel[1] = cum;
    }
  }
}

// K5: fine histogram inside the boundary bin
__global__ __launch_bounds__(256) void k5_fine(const signed char* __restrict__ lab,
                                               uint32_t* __restrict__ ctl,
                                               uint32_t pk0,uint32_t pk1,uint32_t nk0,uint32_t nk1){
  int i = blockIdx.x*256 + threadIdx.x;
  int L = lab[i];
  int ch = (L==1) ? 0 : (L==0) ? 1 : -1;
  if (ch < 0) return;
  const uint32_t* sel = ctl + CTL_SEL + ch*6;
  if (sel[3]) return;
  uint32_t m = rand_m23(ch==0?pk0:nk0, ch==0?pk1:nk1, i);
  if ((m>>11) == sel[0]) atomicAdd(&ctl[CTL_FINE + ch*2048 + (m & 2047u)], 1u);
}

// K6: exact threshold key T and count kept at T.
__global__ __launch_bounds__(256) void k6_scan(uint32_t* __restrict__ ctl){
  __shared__ uint32_t gsum[128];
  int ch = (threadIdx.x >> 6) & 1, grp = threadIdx.x & 63;
  if (threadIdx.x < 128){
    const uint32_t* fine = ctl + CTL_FINE + ch*2048;
    uint32_t s = 0;
    #pragma unroll
    for (int b = 0; b < 32; ++b) s += fine[grp*32 + b];
    gsum[threadIdx.x] = s;
  }
  __syncthreads();
  if (threadIdx.x < 2){
    int c = threadIdx.x;
    uint32_t* sel = ctl + CTL_SEL + c*6;
    if (!sel[3]){
      uint32_t keepRem = sel[2] - sel[1];
      uint32_t cum = 0; int G = 0;
      for (int gq = 63; gq >= 0; --gq){
        uint32_t gc = gsum[c*64 + gq];
        if (cum + gc >= keepRem){ G = gq; break; }
        cum += gc;
      }
      const uint32_t* fine = ctl + CTL_FINE + c*2048;
      int Lb = G*32;
      for (int b = G*32+31; b >= G*32; --b){
        uint32_t bc = fine[b];
        if (cum + bc >= keepRem){ Lb = b; break; }
        cum += bc;
      }
      sel[4] = (sel[0] << 11) | (uint32_t)Lb;
      sel[5] = keepRem - cum;   // >= 1
    }
  }
}

// K7: write final labels (f32) except exact-tie indices (collected for K8)
__global__ __launch_bounds__(256) void k7_final(const signed char* __restrict__ lab,
                                                float* __restrict__ out,
                                                uint32_t* __restrict__ ctl,
                                                uint32_t pk0,uint32_t pk1,uint32_t nk0,uint32_t nk1){
  int i = blockIdx.x*256 + threadIdx.x;
  int L = lab[i];
  float v = (float)L;
  int ch = (L==1) ? 0 : (L==0) ? 1 : -1;
  if (ch >= 0){
    const uint32_t* sel = ctl + CTL_SEL + ch*6;
    if (!sel[3]){
      uint32_t m = rand_m23(ch==0?pk0:nk0, ch==0?pk1:nk1, i);
      uint32_t T = sel[4];
      if (m < T) v = -1.0f;               // demoted
      else if (m == T){                   // tie at threshold: resolve by index in K8
        uint32_t pos = atomicAdd(&ctl[CTL_EQCNT+ch], 1u);
        if (pos < 256u) ctl[CTL_EQL + ch*256 + pos] = (uint32_t)i;
        return;
      }
    }
  }
  out[i] = v;
}

// K8: sort tie lists by index (stable argsort tie-break), keep first needAtT
__global__ void k8_eq(float* __restrict__ out, uint32_t* __restrict__ ctl){
  if (threadIdx.x != 0) return;
  for (int ch = 0; ch < 2; ++ch){
    uint32_t n = ctl[CTL_EQCNT+ch]; if (n > 256u) n = 256u;
    uint32_t* lst = ctl + CTL_EQL + ch*256;
    uint32_t need = ctl[CTL_SEL + ch*6 + 5];
    for (uint32_t a = 1; a < n; ++a){       // insertion sort ascending (n is tiny)
      uint32_t v = lst[a]; int b = (int)a - 1;
      while (b >= 0 && lst[b] > v){ lst[b+1] = lst[b]; --b; }
      lst[b+1] = v;
    }
    float kv = (ch==0) ? 1.0f : 0.0f;
    for (uint32_t a = 0; a < n; ++a)
      out[lst[a]] = (a < need) ? kv : -1.0f;
  }
}

extern "C" void kernel_launch(void* const* d_in, const int* in_sizes, int n_in,
                              void* d_out, int out_size, void* d_ws, size_t ws_size,
                              hipStream_t stream) {
  const float* gt   = (const float*)d_in[1];   // (1,128,4)
  const float* meta = (const float*)d_in[2];   // (1,3) = {H, W, scale}
  float* out = (float*)d_out;                  // labels (147456) + targets (147456*4)
  signed char* lab = (signed char*)d_ws;                       // N_ANCH bytes
  uint32_t* ctl = (uint32_t*)((char*)d_ws + N_ANCH);           // CTL_WORDS u32
  unsigned long long* gmax = (unsigned long long*)(ctl + CTL_GTMAX);

  hipMemsetAsync(ctl, 0, CTL_WORDS * sizeof(uint32_t), stream);

  // jax.random.key(42) = (0,42); partitionable split (foldlike):
  // counts (hi,lo) = (0,0) and (0,1); key_i = (o0, o1) of enc(0, i).
  uint32_t a0,a1,b0,b1;
  tf2x32(0u, 42u, 0u, 0u, &a0, &a1);   // k1 (positives)
  tf2x32(0u, 42u, 0u, 1u, &b0, &b1);   // k2 (negatives)

  k1_anchor<<<576, 256, 0, stream>>>(gt, meta, lab, out);
  k2_gtmax <<<NGT*8, 256, 0, stream>>>(gt, meta, gmax);
  k2b_mark <<<1, NGT, 0, stream>>>(gmax, lab);
  k3_count <<<576, 256, 0, stream>>>(lab, ctl, a0, a1, b0, b1);
  k4_coarse<<<1, 256, 0, stream>>>(ctl);
  k5_fine  <<<576, 256, 0, stream>>>(lab, ctl, a0, a1, b0, b1);
  k6_scan  <<<1, 256, 0, stream>>>(ctl);
  k7_final <<<576, 256, 0, stream>>>(lab, out, ctl, a0, a1, b0, b1);
  k8_eq    <<<1, 1, 0, stream>>>(out, ctl);
}

// Round 6
// 78.907 us; speedup vs baseline: 19.4498x; 1.0596x over previous
//
#include <hip/hip_runtime.h>
#include <stdint.h>

#define N_ANCH 147456
#define NGT 128

// d_ws layout: lab (N_ANCH bytes) | keys (N_ANCH u32) | ctl (CTL_WORDS u32)
// ctl (uint32) word offsets:
#define CTL_SEL    2      // 2 ch x 6 {B, cumAbove, keep, keepAll, T, needAtT}
#define CTL_EQCNT  14     // [2]
#define CTL_EQL    16     // 2 x 256 equal-key index lists
#define CTL_COARSE 528    // 2 x 4096
#define CTL_FINE   8720   // 2 x 2048
#define CTL_GTMAX  12816  // 128 x u64 (256 words; byte offset multiple of 8)
#define CTL_WORDS  13072

__constant__ float c_base[9][4] = {
  {-84.f,-40.f,99.f,55.f},     // r=0.5 s=8
  {-176.f,-88.f,191.f,103.f},  // r=0.5 s=16
  {-360.f,-184.f,375.f,199.f}, // r=0.5 s=32
  {-56.f,-56.f,71.f,71.f},     // r=1   s=8
  {-120.f,-120.f,135.f,135.f}, // r=1   s=16
  {-248.f,-248.f,263.f,263.f}, // r=1   s=32
  {-36.f,-80.f,51.f,95.f},     // r=2   s=8
  {-80.f,-168.f,95.f,183.f},   // r=2   s=16
  {-168.f,-344.f,183.f,359.f}, // r=2   s=32
};

__host__ __device__ inline uint32_t rotl32(uint32_t v, int d){ return (v<<d)|(v>>(32-d)); }

// JAX Threefry-2x32, 20 rounds (5 groups of 4)
__host__ __device__ inline void tf2x32(uint32_t k0, uint32_t k1, uint32_t x0, uint32_t x1,
                                       uint32_t* o0, uint32_t* o1){
  uint32_t ks0=k0, ks1=k1, ks2=k0^k1^0x1BD11BDAu;
  x0 += ks0; x1 += ks1;
  #define TFR(r) { x0 += x1; x1 = rotl32(x1,(r)); x1 ^= x0; }
  TFR(13) TFR(15) TFR(26) TFR(6)   x0+=ks1; x1+=ks2+1u;
  TFR(17) TFR(29) TFR(16) TFR(24)  x0+=ks2; x1+=ks0+2u;
  TFR(13) TFR(15) TFR(26) TFR(6)   x0+=ks0; x1+=ks1+3u;
  TFR(17) TFR(29) TFR(16) TFR(24)  x0+=ks1; x1+=ks2+4u;
  TFR(13) TFR(15) TFR(26) TFR(6)   x0+=ks2; x1+=ks0+5u;
  #undef TFR
  *o0=x0; *o1=x1;
}

// jax_threefry_partitionable=True (default since JAX 0.4.36):
// random_bits(key,32,(n,)) element j: enc(hi=0, lo=j) -> o0 ^ o1; key = top 23 bits.
__device__ inline uint32_t rand_m23(uint32_t k0, uint32_t k1, int j){
  uint32_t a, b;
  tf2x32(k0, k1, 0u, (uint32_t)j, &a, &b);
  return (a ^ b) >> 9;
}

// IoU with +1 convention; __fmul_rn pins rounding so K1/K2 agree bitwise
__device__ inline float iou_box(float ax1,float ay1,float ax2,float ay2,
                                float bx1,float by1,float bx2,float by2){
  float iw = fminf(ax2,bx2) - fmaxf(ax1,bx1) + 1.0f; iw = fmaxf(iw, 0.0f);
  float ih = fminf(ay2,by2) - fmaxf(ay1,by1) + 1.0f; ih = fmaxf(ih, 0.0f);
  float inter = __fmul_rn(iw, ih);
  float areaA = __fmul_rn(ax2-ax1+1.0f, ay2-ay1+1.0f);
  float areaB = __fmul_rn(bx2-bx1+1.0f, by2-by1+1.0f);
  return inter / ((areaA + areaB) - inter);
}

// K1: zero ctl; per-anchor max/argmax over gt; labels, Threefry key, targets
__global__ __launch_bounds__(256) void k1_anchor(const float* __restrict__ gt,
                                                 const float* __restrict__ meta,
                                                 signed char* __restrict__ lab,
                                                 uint32_t* __restrict__ keys,
                                                 uint32_t* __restrict__ ctl,
                                                 float* __restrict__ out,
                                                 uint32_t pk0,uint32_t pk1,
                                                 uint32_t nk0,uint32_t nk1){
  __shared__ float sg[NGT*4];
  for (int t = threadIdx.x; t < NGT*4; t += 256) sg[t] = gt[t];
  __syncthreads();
  int i = blockIdx.x*256 + threadIdx.x;
  if (i < CTL_WORDS) ctl[i] = 0;   // k1 never reads ctl; later kernels are stream-ordered
  float W = meta[1], H = meta[0];
  int k = i / 9; int t9 = i - k*9;
  float sx = 16.0f * (float)(k & 127);
  float sy = 16.0f * (float)(k >> 7);
  float ax1 = c_base[t9][0] + sx, ay1 = c_base[t9][1] + sy;
  float ax2 = c_base[t9][2] + sx, ay2 = c_base[t9][3] + sy;
  bool inside = (ax1 >= 0.0f) && (ay1 >= 0.0f) && (ax2 < W) && (ay2 < H);
  float best = -1.0f; int arg = 0;   // outside: overlaps all -1 -> argmax 0
  if (inside){
    best = -2.0f;
    for (int g = 0; g < NGT; ++g){
      float ov = iou_box(ax1,ay1,ax2,ay2, sg[4*g],sg[4*g+1],sg[4*g+2],sg[4*g+3]);
      if (ov > best){ best = ov; arg = g; }   // strict > = first-occurrence argmax
    }
  }
  signed char L = -1;
  if (best >= 0.7f) L = 1;
  else if (inside && best < 0.3f) L = 0;
  lab[i] = L;
  if (L >= 0)
    keys[i] = (L==1) ? rand_m23(pk0,pk1,i) : rand_m23(nk0,nk1,i);
  float4 t4 = make_float4(0.f, 0.f, 0.f, 0.f);
  if (inside){
    float bx1=sg[4*arg], by1=sg[4*arg+1], bx2=sg[4*arg+2], by2=sg[4*arg+3];
    float ew = ax2-ax1+1.0f, eh = ay2-ay1+1.0f;
    float ecx = ax1 + 0.5f*ew, ecy = ay1 + 0.5f*eh;
    float gw = bx2-bx1+1.0f, gh = by2-by1+1.0f;
    float gcx = bx1 + 0.5f*gw, gcy = by1 + 0.5f*gh;
    t4.x = (gcx-ecx)/ew; t4.y = (gcy-ecy)/eh;
    t4.z = logf(gw/ew);  t4.w = logf(gh/eh);
  }
  *reinterpret_cast<float4*>(out + N_ANCH + 4*(size_t)i) = t4;
}

// K2: per-gt argmax over anchors, 8 slice-blocks per gt, packed-u64 atomicMax.
// pack = (iou_bits << 32) | ~index  -> max = (max iou, then min index); iou >= 0.
__global__ __launch_bounds__(256) void k2_gtmax(const float* __restrict__ gt,
                                                const float* __restrict__ meta,
                                                unsigned long long* __restrict__ gmax){
  int g = blockIdx.x >> 3, slice = blockIdx.x & 7;
  float bx1=gt[4*g], by1=gt[4*g+1], bx2=gt[4*g+2], by2=gt[4*g+3];
  float W = meta[1], H = meta[0];
  float a0[9],a1[9],a2[9],a3[9];
  #pragma unroll
  for (int t=0;t<9;++t){ a0[t]=c_base[t][0]; a1[t]=c_base[t][1];
                         a2[t]=c_base[t][2]; a3[t]=c_base[t][3]; }
  float best = -2.0f; int bi = 0;
  int kbase = slice*2048 + threadIdx.x;
  #pragma unroll
  for (int j = 0; j < 8; ++j){
    int k = kbase + j*256;
    float sx = 16.0f * (float)(k & 127);
    float sy = 16.0f * (float)(k >> 7);
    #pragma unroll
    for (int t = 0; t < 9; ++t){
      float ax1=a0[t]+sx, ay1=a1[t]+sy, ax2=a2[t]+sx, ay2=a3[t]+sy;
      bool inside = (ax1 >= 0.0f) && (ay1 >= 0.0f) && (ax2 < W) && (ay2 < H);
      float ov = inside ? iou_box(ax1,ay1,ax2,ay2,bx1,by1,bx2,by2) : -1.0f;
      if (ov > best){ best = ov; bi = k*9 + t; }   // j,t ascending -> min idx on tie
    }
  }
  unsigned long long p = 0ull;
  if (best >= 0.0f)
    p = ((unsigned long long)__float_as_uint(best) << 32) | (uint32_t)(~(uint32_t)bi);
  __shared__ unsigned long long sred[256];
  sred[threadIdx.x] = p;
  __syncthreads();
  for (int s = 128; s > 0; s >>= 1){
    if ((int)threadIdx.x < s){
      unsigned long long q = sred[threadIdx.x + s];
      if (q > sred[threadIdx.x]) sred[threadIdx.x] = q;
    }
    __syncthreads();
  }
  if (threadIdx.x == 0 && sred[0]) atomicMax(&gmax[g], sred[0]);
}

// K2b: winners -> label 1, re-key under positive channel (idempotent across dup winners)
__global__ void k2b_mark(const unsigned long long* __restrict__ gmax,
                         signed char* __restrict__ lab,
                         uint32_t* __restrict__ keys,
                         uint32_t pk0, uint32_t pk1){
  int g = threadIdx.x;
  unsigned long long p = gmax[g];
  if (p){
    uint32_t idx = ~(uint32_t)(p & 0xFFFFFFFFull);
    lab[idx] = 1;
    keys[idx] = rand_m23(pk0, pk1, (int)idx);
  }
}

// K3: coarse histogram of stored keys per channel (spread atomics, no crypto)
__global__ __launch_bounds__(256) void k3_hist(const signed char* __restrict__ lab,
                                               const uint32_t* __restrict__ keys,
                                               uint32_t* __restrict__ ctl){
  int i = blockIdx.x*256 + threadIdx.x;
  int L = lab[i];
  if (L < 0) return;
  int ch = (L==1) ? 0 : 1;
  atomicAdd(&ctl[CTL_COARSE + ch*4096 + (keys[i]>>11)], 1u);
}

// K4: per-channel count (histogram reduction), keep count, coarse boundary bin.
__global__ __launch_bounds__(256) void k4_coarse(uint32_t* __restrict__ ctl){
  __shared__ uint32_t gsum[256];
  __shared__ uint32_t scnt[2];
  int ch = threadIdx.x >> 7, grp = threadIdx.x & 127;
  const uint32_t* hist = ctl + CTL_COARSE + ch*4096;
  uint32_t s = 0;
  #pragma unroll
  for (int b = 0; b < 32; ++b) s += hist[grp*32 + b];
  gsum[threadIdx.x] = s;
  __syncthreads();
  if ((threadIdx.x & 127) == 0){
    uint32_t cnt = 0;
    for (int gq = 0; gq < 128; ++gq) cnt += gsum[ch*128 + gq];
    scnt[ch] = cnt;
  }
  __syncthreads();
  if (threadIdx.x < 2){
    int c = threadIdx.x;
    uint32_t cntP = scnt[0];
    uint32_t cnt  = scnt[c];
    uint32_t keepP = cntP < 128u ? cntP : 128u;                         // min(n_pos,128)
    uint32_t keep  = (c==0) ? keepP
                            : ((cnt < 256u-keepP) ? cnt : 256u-keepP);  // min(n_neg,256-n_pos)
    uint32_t* sel = ctl + CTL_SEL + c*6;
    sel[2] = keep;
    if (keep >= cnt){ sel[3] = 1u; }
    else {
      sel[3] = 0u;
      uint32_t cum = 0; int G = 0;
      for (int gq = 127; gq >= 0; --gq){
        uint32_t gc = gsum[c*128 + gq];
        if (cum + gc >= keep){ G = gq; break; }
        cum += gc;
      }
      const uint32_t* h = ctl + CTL_COARSE + c*4096;
      int B = G*32;
      for (int b = G*32+31; b >= G*32; --b){
        uint32_t bc = h[b];
        if (cum + bc >= keep){ B = b; break; }
        cum += bc;
      }
      sel[0] = (uint32_t)B; sel[1] = cum;
    }
  }
}

// K5: fine histogram inside the boundary bin
__global__ __launch_bounds__(256) void k5_fine(const signed char* __restrict__ lab,
                                               const uint32_t* __restrict__ keys,
                                               uint32_t* __restrict__ ctl){
  int i = blockIdx.x*256 + threadIdx.x;
  int L = lab[i];
  int ch = (L==1) ? 0 : (L==0) ? 1 : -1;
  if (ch < 0) return;
  const uint32_t* sel = ctl + CTL_SEL + ch*6;
  if (sel[3]) return;
  uint32_t m = keys[i];
  if ((m>>11) == sel[0]) atomicAdd(&ctl[CTL_FINE + ch*2048 + (m & 2047u)], 1u);
}

// K6: exact threshold key T and count kept at T.
__global__ __launch_bounds__(256) void k6_scan(uint32_t* __restrict__ ctl){
  __shared__ uint32_t gsum[128];
  int ch = (threadIdx.x >> 6) & 1, grp = threadIdx.x & 63;
  if (threadIdx.x < 128){
    const uint32_t* fine = ctl + CTL_FINE + ch*2048;
    uint32_t s = 0;
    #pragma unroll
    for (int b = 0; b < 32; ++b) s += fine[grp*32 + b];
    gsum[threadIdx.x] = s;
  }
  __syncthreads();
  if (threadIdx.x < 2){
    int c = threadIdx.x;
    uint32_t* sel = ctl + CTL_SEL + c*6;
    if (!sel[3]){
      uint32_t keepRem = sel[2] - sel[1];
      uint32_t cum = 0; int G = 0;
      for (int gq = 63; gq >= 0; --gq){
        uint32_t gc = gsum[c*64 + gq];
        if (cum + gc >= keepRem){ G = gq; break; }
        cum += gc;
      }
      const uint32_t* fine = ctl + CTL_FINE + c*2048;
      int Lb = G*32;
      for (int b = G*32+31; b >= G*32; --b){
        uint32_t bc = fine[b];
        if (cum + bc >= keepRem){ Lb = b; break; }
        cum += bc;
      }
      sel[4] = (sel[0] << 11) | (uint32_t)Lb;
      sel[5] = keepRem - cum;   // >= 1
    }
  }
}

// K7: write final labels (f32) except exact-tie indices (collected for K8)
__global__ __launch_bounds__(256) void k7_final(const signed char* __restrict__ lab,
                                                const uint32_t* __restrict__ keys,
                                                float* __restrict__ out,
                                                uint32_t* __restrict__ ctl){
  int i = blockIdx.x*256 + threadIdx.x;
  int L = lab[i];
  float v = (float)L;
  int ch = (L==1) ? 0 : (L==0) ? 1 : -1;
  if (ch >= 0){
    const uint32_t* sel = ctl + CTL_SEL + ch*6;
    if (!sel[3]){
      uint32_t m = keys[i];
      uint32_t T = sel[4];
      if (m < T) v = -1.0f;               // demoted
      else if (m == T){                   // tie at threshold: resolve by index in K8
        uint32_t pos = atomicAdd(&ctl[CTL_EQCNT+ch], 1u);
        if (pos < 256u) ctl[CTL_EQL + ch*256 + pos] = (uint32_t)i;
        return;
      }
    }
  }
  out[i] = v;
}

// K8: sort tie lists by index (stable argsort tie-break), keep first needAtT
__global__ void k8_eq(float* __restrict__ out, uint32_t* __restrict__ ctl){
  if (threadIdx.x != 0) return;
  for (int ch = 0; ch < 2; ++ch){
    uint32_t n = ctl[CTL_EQCNT+ch]; if (n > 256u) n = 256u;
    uint32_t* lst = ctl + CTL_EQL + ch*256;
    uint32_t need = ctl[CTL_SEL + ch*6 + 5];
    for (uint32_t a = 1; a < n; ++a){       // insertion sort ascending (n is tiny)
      uint32_t v = lst[a]; int b = (int)a - 1;
      while (b >= 0 && lst[b] > v){ lst[b+1] = lst[b]; --b; }
      lst[b+1] = v;
    }
    float kv = (ch==0) ? 1.0f : 0.0f;
    for (uint32_t a = 0; a < n; ++a)
      out[lst[a]] = (a < need) ? kv : -1.0f;
  }
}

extern "C" void kernel_launch(void* const* d_in, const int* in_sizes, int n_in,
                              void* d_out, int out_size, void* d_ws, size_t ws_size,
                              hipStream_t stream) {
  const float* gt   = (const float*)d_in[1];   // (1,128,4)
  const float* meta = (const float*)d_in[2];   // (1,3) = {H, W, scale}
  float* out = (float*)d_out;                  // labels (147456) + targets (147456*4)
  signed char* lab = (signed char*)d_ws;                                 // N_ANCH B
  uint32_t* keys = (uint32_t*)((char*)d_ws + N_ANCH);                    // N_ANCH u32
  uint32_t* ctl  = keys + N_ANCH;                                        // CTL_WORDS u32
  unsigned long long* gmax = (unsigned long long*)(ctl + CTL_GTMAX);

  // jax.random.key(42) = (0,42); partitionable split (foldlike):
  // counts (hi,lo) = (0,0) and (0,1); key_i = (o0, o1) of enc(0, i).
  uint32_t a0,a1,b0,b1;
  tf2x32(0u, 42u, 0u, 0u, &a0, &a1);   // k1 (positives)
  tf2x32(0u, 42u, 0u, 1u, &b0, &b1);   // k2 (negatives)

  k1_anchor<<<576, 256, 0, stream>>>(gt, meta, lab, keys, ctl, out, a0, a1, b0, b1);
  k2_gtmax <<<NGT*8, 256, 0, stream>>>(gt, meta, gmax);
  k2b_mark <<<1, NGT, 0, stream>>>(gmax, lab, keys, a0, a1);
  k3_hist  <<<576, 256, 0, stream>>>(lab, keys, ctl);
  k4_coarse<<<1, 256, 0, stream>>>(ctl);
  k5_fine  <<<576, 256, 0, stream>>>(lab, keys, ctl);
  k6_scan  <<<1, 256, 0, stream>>>(ctl);
  k7_final <<<576, 256, 0, stream>>>(lab, keys, out, ctl);
  k8_eq    <<<1, 1, 0, stream>>>(out, ctl);
}